// Round 2
// baseline (460.237 us; speedup 1.0000x reference)
//
#include <hip/hip_runtime.h>

#define N_NODES 100000
#define N_EDGES 800000
#define NF 81
#define NB 22
#define OC 64

// Fused node pass: out[n] = feat[n]@w_s ; pb[n] = feat[n]@w_n[:81] ;
// xyz[n] = feat[n,0:3] packed (1.6 MB -> L2-resident for the edge pass).
// Wave per node, lane = channel; both weight columns register-resident
// (~162 VGPRs), feat row scalarized -> s_load batches; two independent
// 81-deep fmac chains give 2x ILP on the VALU.
__global__ __launch_bounds__(256, 2) void k_nodes(
    const float* __restrict__ feat, const float* __restrict__ w_s,
    const float* __restrict__ w_n, float* __restrict__ out,
    float* __restrict__ pb, float4* __restrict__ xyz)
{
    const int lane = threadIdx.x & 63;
    const int wid  = (int)((blockIdx.x * blockDim.x + threadIdx.x) >> 6);
    const int nw   = (int)((gridDim.x * blockDim.x) >> 6);

    float wsc[NF], wnc[NF];
#pragma unroll
    for (int k = 0; k < NF; ++k) {
        wsc[k] = w_s[k * OC + lane];
        wnc[k] = w_n[k * OC + lane];
    }

    for (int n = wid; n < N_NODES; n += nw) {
        const int nu = __builtin_amdgcn_readfirstlane(n);
        const float* f = feat + (long)nu * NF;
        float a0 = 0.f, a1 = 0.f;
        float f0 = 0.f, f1 = 0.f, f2 = 0.f;
#pragma unroll
        for (int k = 0; k < NF; ++k) {
            const float fv = f[k];
            if (k == 0) f0 = fv;
            if (k == 1) f1 = fv;
            if (k == 2) f2 = fv;
            a0 += fv * wsc[k];
            a1 += fv * wnc[k];
        }
        out[(long)nu * OC + lane] = a0;
        pb [(long)nu * OC + lane] = a1;
        if (lane == 0) xyz[nu] = make_float4(f0, f1, f2, 0.f);
    }
}

// Edge pass: wave per TWO edges (pair-contiguous so src/dst/bond batch into
// wider scalar loads), lane = channel.
// contrib = inv_d2*(PA[s] + PB[t]) + bond[e] @ w_n[81:103]
// PA[s] = PB[s] - (x*w0 + y*w1 + z*w2). No launch_bounds: let the register
// allocator keep wnb[22] + two edges' loads in flight.
__global__ void k_edge(
    const float* __restrict__ bond, const float* __restrict__ w_n,
    const int* __restrict__ src, const int* __restrict__ dst,
    const float* __restrict__ pb, const float4* __restrict__ xyz,
    float* __restrict__ out)
{
    const int lane = threadIdx.x & 63;
    const int wid  = (int)((blockIdx.x * blockDim.x + threadIdx.x) >> 6);
    const int nw   = (int)((gridDim.x * blockDim.x) >> 6);

    float wnb[NB];
#pragma unroll
    for (int j = 0; j < NB; ++j) wnb[j] = w_n[(NF + j) * OC + lane];
    const float w0 = w_n[0 * OC + lane];
    const float w1 = w_n[1 * OC + lane];
    const float w2 = w_n[2 * OC + lane];

    const int NPAIR = N_EDGES / 2;
    for (int p = wid; p < NPAIR; p += nw) {
        const int e = __builtin_amdgcn_readfirstlane(p * 2);

        // scalar index loads (adjacent pair -> one dwordx2 each)
        const int sA = src[e],     sB = src[e + 1];
        const int tA = dst[e],     tB = dst[e + 1];

        // second memory round: everything issued together
        const float4 xsA = xyz[sA], xtA = xyz[tA];
        const float4 xsB = xyz[sB], xtB = xyz[tB];
        const float pbsA = pb[(long)sA * OC + lane];
        const float pbtA = pb[(long)tA * OC + lane];
        const float pbsB = pb[(long)sB * OC + lane];
        const float pbtB = pb[(long)tB * OC + lane];
        const float* bA = bond + (long)e * NB;   // 176 contiguous bytes
        const float* bB = bA + NB;

        float dx, dy, dz;
        dx = xsA.x - xtA.x; dy = xsA.y - xtA.y; dz = xsA.z - xtA.z;
        const float d2A = dx * dx + dy * dy + dz * dz;
        dx = xsB.x - xtB.x; dy = xsB.y - xtB.y; dz = xsB.z - xtB.z;
        const float d2B = dx * dx + dy * dy + dz * dz;
        const float invA = (d2A > 0.f) ? __builtin_amdgcn_rcpf(d2A) : 1.0e4f;
        const float invB = (d2B > 0.f) ? __builtin_amdgcn_rcpf(d2B) : 1.0e4f;

        float accA = (pbsA - (xsA.x * w0 + xsA.y * w1 + xsA.z * w2) + pbtA) * invA;
        float accB = (pbsB - (xsB.x * w0 + xsB.y * w1 + xsB.z * w2) + pbtB) * invB;
#pragma unroll
        for (int j = 0; j < NB; ++j) {
            accA += bA[j] * wnb[j];
            accB += bB[j] * wnb[j];
        }

        unsafeAtomicAdd(&out[(long)sA * OC + lane], accA);
        unsafeAtomicAdd(&out[(long)sB * OC + lane], accB);
    }
}

extern "C" void kernel_launch(void* const* d_in, const int* in_sizes, int n_in,
                              void* d_out, int out_size, void* d_ws, size_t ws_size,
                              hipStream_t stream) {
    const float* feat = (const float*)d_in[0];
    const float* bond = (const float*)d_in[1];
    const float* w_s  = (const float*)d_in[2];
    const float* w_n  = (const float*)d_in[3];
    const int*   src  = (const int*)d_in[4];
    const int*   dstv = (const int*)d_in[5];
    float* out = (float*)d_out;

    float*  pb  = (float*)d_ws;                       // 25.6 MB
    float4* xyz = (float4*)((char*)d_ws + (size_t)N_NODES * OC * sizeof(float)); // +1.6 MB

    k_nodes<<<1024, 256, 0, stream>>>(feat, w_s, w_n, out, pb, xyz);
    k_edge <<<2048, 256, 0, stream>>>(bond, w_n, src, dstv, pb, xyz, out);
}